// Round 16
// baseline (502.780 us; speedup 1.0000x reference)
//
#include <hip/hip_runtime.h>

#define B_ 64
#define T_ 512
#define F_ 1024
#define U_ 64
#define FK 128            // k-chunk staged in LDS (GEMM)
#define NCH (F_ / FK)     // 8 chunks

// DPP quad_perm helpers (validated R4): single-VALU cross-lane exchange in
// each quad. 0xB1 = [1,0,3,2] (xor 1), 0x4E = [2,3,0,1] (xor 2).
template <int CTRL>
__device__ __forceinline__ int dpp_qp_i(int x) {
    return __builtin_amdgcn_update_dpp(0, x, CTRL, 0xF, 0xF, true);
}
template <int CTRL>
__device__ __forceinline__ float dpp_qp_f(float x) {
    return __int_as_float(
        __builtin_amdgcn_update_dpp(0, __float_as_int(x), CTRL, 0xF, 0xF, true));
}

// ---------------------------------------------------------------------------
// Kernel 1: potentials = x @ w + bias (+ boundaries).  32768 x 64.
// VERBATIM round-5 kernel (validated 5x, ~108us): 64-row block, 4 rows x
// 4 cols per thread, grid 512, plain row mapping (R15: XCD relabel = null).
// w staged K-chunk-wise into LDS (32 KB). Per-output accumulation:
// ascending f, sequential fmaf (bit-identical to all validated rounds).
// ---------------------------------------------------------------------------
__global__ __launch_bounds__(256, 2) void crf_gemm_kernel(
    const float* __restrict__ x, const float* __restrict__ w,
    const float* __restrict__ bias, const float* __restrict__ lb,
    const float* __restrict__ rb, float* __restrict__ pot)
{
    __shared__ float wlds[FK * U_];     // 32 KB, [k][u] row-major

    const int tid = threadIdx.x;
    const int rt = tid >> 4;            // 16 row-groups x 4 rows
    const int ut = tid & 15;            // 16 col-groups x 4 cols
    const int n0 = blockIdx.x * 64;
    const int r0 = rt * 4;
    const int u0 = ut * 4;

    float acc[4][4];
#pragma unroll
    for (int i = 0; i < 4; ++i)
#pragma unroll
        for (int j = 0; j < 4; ++j) acc[i][j] = 0.f;

    const float* xrow = x + (size_t)(n0 + r0) * F_;

    // ---- stage chunk 0 ----
    float4 wst[8];
#pragma unroll
    for (int l = 0; l < 8; ++l)
        wst[l] = *reinterpret_cast<const float4*>(w + (size_t)(l * 256 + tid) * 4);
#pragma unroll
    for (int l = 0; l < 8; ++l)
        *reinterpret_cast<float4*>(&wlds[(l * 256 + tid) * 4]) = wst[l];
    __syncthreads();

    // ---- x distance-2 register pipeline (global-k indexed) ----
    float4 xp0[4], xp1[4];
#pragma unroll
    for (int i = 0; i < 4; ++i)
        xp0[i] = *reinterpret_cast<const float4*>(xrow + (size_t)i * F_ + 0);
#pragma unroll
    for (int i = 0; i < 4; ++i)
        xp1[i] = *reinterpret_cast<const float4*>(xrow + (size_t)i * F_ + 4);

    for (int c = 0; c < NCH; ++c) {
        // issue next chunk's stage loads early (land during compute)
        if (c + 1 < NCH) {
#pragma unroll
            for (int l = 0; l < 8; ++l)
                wst[l] = *reinterpret_cast<const float4*>(
                    w + (size_t)(c + 1) * (FK * U_) + (size_t)(l * 256 + tid) * 4);
        }

        // w LDS read, prefetched one iter ahead
        float4 wc[4];
#pragma unroll
        for (int j = 0; j < 4; ++j)
            wc[j] = *reinterpret_cast<const float4*>(&wlds[(0 + j) * U_ + u0]);

        for (int kk = 0; kk < FK / 4; ++kk) {
            // prefetch x at global k = c*128 + kk*4 + 8 (wrap: harmless)
            const int kg = (c * FK + kk * 4 + 8) & (F_ - 1);
            float4 xn[4];
#pragma unroll
            for (int i = 0; i < 4; ++i)
                xn[i] = *reinterpret_cast<const float4*>(xrow + (size_t)i * F_ + kg);

            // prefetch next iter's w rows ((kk+1)*4, wraps to 0 at chunk end)
            float4 wn[4];
            const int krn = (kk * 4 + 4) & (FK - 1);
#pragma unroll
            for (int j = 0; j < 4; ++j)
                wn[j] = *reinterpret_cast<const float4*>(&wlds[(krn + j) * U_ + u0]);

            // 64 FMAs, f ascending per output
#pragma unroll
            for (int ff = 0; ff < 4; ++ff) {
                const float4 wf = wc[ff];
#pragma unroll
                for (int i = 0; i < 4; ++i) {
                    const float xs = (ff == 0) ? xp0[i].x : (ff == 1) ? xp0[i].y
                                   : (ff == 2) ? xp0[i].z : xp0[i].w;
                    acc[i][0] = fmaf(xs, wf.x, acc[i][0]);
                    acc[i][1] = fmaf(xs, wf.y, acc[i][1]);
                    acc[i][2] = fmaf(xs, wf.z, acc[i][2]);
                    acc[i][3] = fmaf(xs, wf.w, acc[i][3]);
                }
            }
#pragma unroll
            for (int i = 0; i < 4; ++i) { xp0[i] = xp1[i]; xp1[i] = xn[i]; }
#pragma unroll
            for (int j = 0; j < 4; ++j) wc[j] = wn[j];
        }

        if (c + 1 < NCH) {
            __syncthreads();            // all reads of current chunk done
#pragma unroll
            for (int l = 0; l < 8; ++l)
                *reinterpret_cast<float4*>(&wlds[(l * 256 + tid) * 4]) = wst[l];
            __syncthreads();
        }
    }

    // ---- epilogue ----
    const int t0 = n0 & (T_ - 1);       // 64 | 512: one batch per block
    const float4 bs4 = *reinterpret_cast<const float4*>(bias + u0);
    const float4 lb4 = *reinterpret_cast<const float4*>(lb + u0);
    const float4 rb4 = *reinterpret_cast<const float4*>(rb + u0);

#pragma unroll
    for (int i = 0; i < 4; ++i) {
        const int n = n0 + r0 + i;
        const int t = t0 + r0 + i;
        float4 o;
        o.x = acc[i][0] + bs4.x;
        o.y = acc[i][1] + bs4.y;
        o.z = acc[i][2] + bs4.z;
        o.w = acc[i][3] + bs4.w;
        if (t == 0)      { o.x += lb4.x; o.y += lb4.y; o.z += lb4.z; o.w += lb4.w; }
        if (t == T_ - 1) { o.x += rb4.x; o.y += rb4.y; o.z += rb4.z; o.w += rb4.w; }
        *reinterpret_cast<float4*>(pot + (size_t)n * U_ + u0) = o;
    }
}

// ---------------------------------------------------------------------------
// Kernel 2: Viterbi -- FOUR BATCHES PER BLOCK for SIMD co-residency.
// 16 blocks x 1024 threads (16 waves). Wave w: sub-batch sb = w>>2,
// wave-role wv = w&3; batch = blockIdx*4 + sb. Per batch the step is the
// R4-original DPP kernel VERBATIM (fastest measured form, 222us, absmax=0):
// u = wv*16 + (lane>>2), vc = lane&3, s[16] static tournament, quad DPP
// combine (lex (val,idx) == jnp first-occurrence), alpha double-buffered,
// ONE block-wide barrier per step (shared by all 4 batches -- they run
// identical step schedules, so coupling is harmless).
// WHY: 64 blocks x 4 waves = 1 wave/SIMD = zero latency hiding (9 variants
// all ~1000cy/step). 4 batches/block -> 4 waves/SIMD: A's LDS/barrier
// latency hides under B/C/D's issue. LDS = 133,952 B (< 160 KiB cap).
// Exact arithmetic: s = (alpha[v] + chain[v][u]) + pot[t][u], strict >,
// ascending v. Segmented 2-pass backtrace per batch (validated).
// ---------------------------------------------------------------------------
__global__ __launch_bounds__(1024) void crf_viterbi_kernel(
    const float* __restrict__ pot, const float* __restrict__ chain,
    int* __restrict__ path)
{
    const int tid = threadIdx.x;
    const int lane = tid & 63;
    const int w = tid >> 6;               // wave 0..15
    const int sb = w >> 2;                // sub-batch 0..3
    const int wv = w & 3;                 // wave-role within batch
    const int b = blockIdx.x * 4 + sb;    // global batch
    const int u = wv * 16 + (lane >> 2);  // output tag this lane serves
    const int vc = lane & 3;              // v-chunk 0..3

    __shared__ __align__(16) float albuf[4][2][64];      //  2 KB
    __shared__ unsigned char bp[4][T_ - 1][64];          // ~128 KB
    __shared__ unsigned char cmap[4][4][64];             //  1 KB
    __shared__ int es[4][4];

    float chain_r[16];
#pragma unroll
    for (int k = 0; k < 16; ++k)
        chain_r[k] = chain[(size_t)(vc * 16 + k) * U_ + u];

    const float* potb = pot + (size_t)b * T_ * U_;
    const bool wr = (vc == 0);

    if (wr) albuf[sb][0][u] = potb[u];    // t = 0 (bias + left included)
    __syncthreads();

    float pc = potb[U_ + u];              // pot[1][u]

    for (int t = 1; t < T_; ++t) {
        // prefetch next pot row (drains inside the barrier wait)
        const int tn = (t + 1 < T_) ? (t + 1) : (T_ - 1);
        const float pn = potb[(size_t)tn * U_ + u];

        const float4* a4 = reinterpret_cast<const float4*>(albuf[sb][(t - 1) & 1]);
        float s[16];
#pragma unroll
        for (int q = 0; q < 4; ++q) {
            const float4 av = a4[vc * 4 + q];
            s[q * 4 + 0] = (av.x + chain_r[q * 4 + 0]) + pc;
            s[q * 4 + 1] = (av.y + chain_r[q * 4 + 1]) + pc;
            s[q * 4 + 2] = (av.z + chain_r[q * 4 + 2]) + pc;
            s[q * 4 + 3] = (av.w + chain_r[q * 4 + 3]) + pc;
        }
        // tournament 16 -> 1: strict >, left (smaller v) wins ties
        float tv[8]; int ti[8];
#pragma unroll
        for (int i = 0; i < 8; ++i) {
            const bool gt = s[2 * i + 1] > s[2 * i];
            tv[i] = gt ? s[2 * i + 1] : s[2 * i];
            ti[i] = gt ? 2 * i + 1 : 2 * i;
        }
        float uv[4]; int ui[4];
#pragma unroll
        for (int i = 0; i < 4; ++i) {
            const bool gt = tv[2 * i + 1] > tv[2 * i];
            uv[i] = gt ? tv[2 * i + 1] : tv[2 * i];
            ui[i] = gt ? ti[2 * i + 1] : ti[2 * i];
        }
        const bool g0 = uv[1] > uv[0];
        const float w0 = g0 ? uv[1] : uv[0];
        const int   i0 = g0 ? ui[1] : ui[0];
        const bool g1 = uv[3] > uv[2];
        const float w1 = g1 ? uv[3] : uv[2];
        const int   i1 = g1 ? ui[3] : ui[2];
        const bool gf = w1 > w0;
        float bv = gf ? w1 : w0;
        int   gi = vc * 16 + (gf ? i1 : i0);   // global v index

        // quad butterfly via DPP: lex (val, idx) max; equal val -> smaller v
        {
            const float ov = dpp_qp_f<0xB1>(bv);   // xor 1
            const int   oi = dpp_qp_i<0xB1>(gi);
            const bool tk = (ov > bv) || (ov == bv && oi < gi);
            bv = tk ? ov : bv;
            gi = tk ? oi : gi;
        }
        {
            const float ov = dpp_qp_f<0x4E>(bv);   // xor 2
            const int   oi = dpp_qp_i<0x4E>(gi);
            const bool tk = (ov > bv) || (ov == bv && oi < gi);
            bv = tk ? ov : bv;
            gi = tk ? oi : gi;
        }

        if (wr) {
            albuf[sb][t & 1][u] = bv;
            bp[sb][t - 1][u] = (unsigned char)gi;
        }
        __syncthreads();
        pc = pn;
    }

    // ---- backtrace (2-pass segmented per batch, integer-exact) ----
    const int r0c = wv * 128;
    const int r1c = (wv == 3) ? (T_ - 1) : (wv + 1) * 128;

    {   // pass 1: composed map of my segment from every possible start tag
        int tag = lane;
        for (int r = r1c - 1; r >= r0c; --r) tag = bp[sb][r][tag];
        cmap[sb][wv][lane] = (unsigned char)tag;
    }
    __syncthreads();

    if (lane == 0 && wv == 0) {
        // final argmax for batch sb (first occurrence); last write was buf[1]
        const float* af = albuf[sb][(T_ - 1) & 1];
        float bvv = af[0];
        int bii = 0;
        for (int v = 1; v < 64; ++v) {
            const float a = af[v];
            if (a > bvv) { bvv = a; bii = v; }
        }
        path[(size_t)b * T_ + (T_ - 1)] = bii;
        const int e3 = bii;                    // tag_511
        const int e2 = cmap[sb][3][e3];        // tag_384
        const int e1 = cmap[sb][2][e2];        // tag_256
        const int e0 = cmap[sb][1][e1];        // tag_128
        es[sb][0] = e0; es[sb][1] = e1; es[sb][2] = e2; es[sb][3] = e3;
    }
    __syncthreads();

    // pass 2: 4 parallel chases per batch over disjoint row ranges (exact
    // replica of the sequential loop: tag_r = bp[r][tag_{r+1}])
    if (lane == 0) {
        int tag = es[sb][wv];                  // tag at row r1c
        int* pb = path + (size_t)b * T_;
        for (int r = r1c - 1; r >= r0c; --r) {
            tag = bp[sb][r][tag];
            pb[r] = tag;
        }
    }
}

extern "C" void kernel_launch(void* const* d_in, const int* in_sizes, int n_in,
                              void* d_out, int out_size, void* d_ws, size_t ws_size,
                              hipStream_t stream) {
    const float* x  = (const float*)d_in[0];
    const float* w  = (const float*)d_in[1];
    const float* bs = (const float*)d_in[2];
    const float* ck = (const float*)d_in[3];
    const float* lb = (const float*)d_in[4];
    const float* rb = (const float*)d_in[5];

    float* pot = (float*)d_ws;          // [B*T][U] f32 = 8.39 MB
    int* path  = (int*)d_out;           // [B][T] int32

    crf_gemm_kernel<<<dim3(B_ * T_ / 64), dim3(256), 0, stream>>>(x, w, bs, lb, rb, pot);
    crf_viterbi_kernel<<<dim3(B_ / 4), dim3(1024), 0, stream>>>(pot, ck, path);
}

// Round 17
// 401.513 us; speedup vs baseline: 1.2522x; 1.2522x over previous
//
#include <hip/hip_runtime.h>

#define B_ 64
#define T_ 512
#define F_ 1024
#define U_ 64
#define FK 128            // k-chunk staged in LDS (GEMM)
#define NCH (F_ / FK)     // 8 chunks

// DPP quad_perm helpers (validated R4): single-VALU cross-lane exchange in
// each quad. 0xB1 = [1,0,3,2] (xor 1), 0x4E = [2,3,0,1] (xor 2).
template <int CTRL>
__device__ __forceinline__ int dpp_qp_i(int x) {
    return __builtin_amdgcn_update_dpp(0, x, CTRL, 0xF, 0xF, true);
}
template <int CTRL>
__device__ __forceinline__ float dpp_qp_f(float x) {
    return __int_as_float(
        __builtin_amdgcn_update_dpp(0, __float_as_int(x), CTRL, 0xF, 0xF, true));
}

// ---------------------------------------------------------------------------
// Kernel 1: potentials = x @ w + bias (+ boundaries).  32768 x 64.
// VERBATIM round-5 kernel (validated 5x, ~108us best measured): 64-row
// block, 4 rows x 4 cols per thread, grid 512 (2 blocks/CU = 2 waves/SIMD;
// R6 proved 4 waves/SIMD is SLOWER for this form). w staged K-chunk-wise
// into LDS (32 KB), next chunk's loads issued before the compute phase.
// Rolling (non-unrolled) kk loop (full unroll spilled, R7). Per-output
// accumulation: ascending f, sequential fmaf. DO NOT TOUCH.
// ---------------------------------------------------------------------------
__global__ __launch_bounds__(256, 2) void crf_gemm_kernel(
    const float* __restrict__ x, const float* __restrict__ w,
    const float* __restrict__ bias, const float* __restrict__ lb,
    const float* __restrict__ rb, float* __restrict__ pot)
{
    __shared__ float wlds[FK * U_];     // 32 KB, [k][u] row-major

    const int tid = threadIdx.x;
    const int rt = tid >> 4;            // 16 row-groups x 4 rows
    const int ut = tid & 15;            // 16 col-groups x 4 cols
    const int n0 = blockIdx.x * 64;
    const int r0 = rt * 4;
    const int u0 = ut * 4;

    float acc[4][4];
#pragma unroll
    for (int i = 0; i < 4; ++i)
#pragma unroll
        for (int j = 0; j < 4; ++j) acc[i][j] = 0.f;

    const float* xrow = x + (size_t)(n0 + r0) * F_;

    // ---- stage chunk 0 ----
    float4 wst[8];
#pragma unroll
    for (int l = 0; l < 8; ++l)
        wst[l] = *reinterpret_cast<const float4*>(w + (size_t)(l * 256 + tid) * 4);
#pragma unroll
    for (int l = 0; l < 8; ++l)
        *reinterpret_cast<float4*>(&wlds[(l * 256 + tid) * 4]) = wst[l];
    __syncthreads();

    // ---- x distance-2 register pipeline (global-k indexed) ----
    float4 xp0[4], xp1[4];
#pragma unroll
    for (int i = 0; i < 4; ++i)
        xp0[i] = *reinterpret_cast<const float4*>(xrow + (size_t)i * F_ + 0);
#pragma unroll
    for (int i = 0; i < 4; ++i)
        xp1[i] = *reinterpret_cast<const float4*>(xrow + (size_t)i * F_ + 4);

    for (int c = 0; c < NCH; ++c) {
        // issue next chunk's stage loads early (land during compute)
        if (c + 1 < NCH) {
#pragma unroll
            for (int l = 0; l < 8; ++l)
                wst[l] = *reinterpret_cast<const float4*>(
                    w + (size_t)(c + 1) * (FK * U_) + (size_t)(l * 256 + tid) * 4);
        }

        // w LDS read, prefetched one iter ahead
        float4 wc[4];
#pragma unroll
        for (int j = 0; j < 4; ++j)
            wc[j] = *reinterpret_cast<const float4*>(&wlds[(0 + j) * U_ + u0]);

        for (int kk = 0; kk < FK / 4; ++kk) {
            // prefetch x at global k = c*128 + kk*4 + 8 (wrap: harmless)
            const int kg = (c * FK + kk * 4 + 8) & (F_ - 1);
            float4 xn[4];
#pragma unroll
            for (int i = 0; i < 4; ++i)
                xn[i] = *reinterpret_cast<const float4*>(xrow + (size_t)i * F_ + kg);

            // prefetch next iter's w rows ((kk+1)*4, wraps to 0 at chunk end)
            float4 wn[4];
            const int krn = (kk * 4 + 4) & (FK - 1);
#pragma unroll
            for (int j = 0; j < 4; ++j)
                wn[j] = *reinterpret_cast<const float4*>(&wlds[(krn + j) * U_ + u0]);

            // 64 FMAs, f ascending per output
#pragma unroll
            for (int ff = 0; ff < 4; ++ff) {
                const float4 wf = wc[ff];
#pragma unroll
                for (int i = 0; i < 4; ++i) {
                    const float xs = (ff == 0) ? xp0[i].x : (ff == 1) ? xp0[i].y
                                   : (ff == 2) ? xp0[i].z : xp0[i].w;
                    acc[i][0] = fmaf(xs, wf.x, acc[i][0]);
                    acc[i][1] = fmaf(xs, wf.y, acc[i][1]);
                    acc[i][2] = fmaf(xs, wf.z, acc[i][2]);
                    acc[i][3] = fmaf(xs, wf.w, acc[i][3]);
                }
            }
#pragma unroll
            for (int i = 0; i < 4; ++i) { xp0[i] = xp1[i]; xp1[i] = xn[i]; }
#pragma unroll
            for (int j = 0; j < 4; ++j) wc[j] = wn[j];
        }

        if (c + 1 < NCH) {
            __syncthreads();            // all reads of current chunk done
#pragma unroll
            for (int l = 0; l < 8; ++l)
                *reinterpret_cast<float4*>(&wlds[(l * 256 + tid) * 4]) = wst[l];
            __syncthreads();
        }
    }

    // ---- epilogue ----
    const int t0 = n0 & (T_ - 1);       // 64 | 512: one batch per block
    const float4 bs4 = *reinterpret_cast<const float4*>(bias + u0);
    const float4 lb4 = *reinterpret_cast<const float4*>(lb + u0);
    const float4 rb4 = *reinterpret_cast<const float4*>(rb + u0);

#pragma unroll
    for (int i = 0; i < 4; ++i) {
        const int n = n0 + r0 + i;
        const int t = t0 + r0 + i;
        float4 o;
        o.x = acc[i][0] + bs4.x;
        o.y = acc[i][1] + bs4.y;
        o.z = acc[i][2] + bs4.z;
        o.w = acc[i][3] + bs4.w;
        if (t == 0)      { o.x += lb4.x; o.y += lb4.y; o.z += lb4.z; o.w += lb4.w; }
        if (t == T_ - 1) { o.x += rb4.x; o.y += rb4.y; o.z += rb4.z; o.w += rb4.w; }
        *reinterpret_cast<float4*>(pot + (size_t)n * U_ + u0) = o;
    }
}

// ---------------------------------------------------------------------------
// Kernel 2: Viterbi, one block (4 waves) per batch. VERBATIM R4 DPP kernel
// -- the best-measured viterbi (222us, absmax=0): thread (wave, lane) ->
// u = wv*16 + (lane>>2), vc = lane&3; static s[16] tournament (strict >,
// ascending v == jnp.argmax first occurrence); quad DPP combine (lex
// (val,idx)); alpha double-buffered -> ONE __syncthreads per step (lgkm-only
// barriers lose ~70us, proven R5/R11; bank conflicts are free, proven R15).
// Segmented 2-pass backtrace (validated, integer-exact).
// Exact arithmetic: s = (alpha[v] + chain[v][u]) + pot[t][u].
// ---------------------------------------------------------------------------
__global__ __launch_bounds__(256) void crf_viterbi_kernel(
    const float* __restrict__ pot, const float* __restrict__ chain,
    int* __restrict__ path)
{
    const int b = blockIdx.x;
    const int tid = threadIdx.x;
    const int lane = tid & 63;
    const int wv = tid >> 6;              // wave 0..3
    const int u = wv * 16 + (lane >> 2);  // output tag this lane serves
    const int vc = lane & 3;              // v-chunk 0..3

    __shared__ __align__(16) float albuf[2][64];
    __shared__ unsigned char bp[T_ - 1][64];   // 32704 B
    __shared__ unsigned char cmap[4][64];
    __shared__ int es[4];

    float chain_r[16];
#pragma unroll
    for (int k = 0; k < 16; ++k)
        chain_r[k] = chain[(size_t)(vc * 16 + k) * U_ + u];

    const float* potb = pot + (size_t)b * T_ * U_;
    const bool wr = (vc == 0);

    if (wr) albuf[0][u] = potb[u];        // t = 0 (bias + left included)
    __syncthreads();

    float pc = potb[U_ + u];              // pot[1][u]

    for (int t = 1; t < T_; ++t) {
        // prefetch next pot row (drains inside the barrier wait)
        const int tn = (t + 1 < T_) ? (t + 1) : (T_ - 1);
        const float pn = potb[(size_t)tn * U_ + u];

        const float4* a4 = reinterpret_cast<const float4*>(albuf[(t - 1) & 1]);
        float s[16];
#pragma unroll
        for (int q = 0; q < 4; ++q) {
            const float4 av = a4[vc * 4 + q];
            s[q * 4 + 0] = (av.x + chain_r[q * 4 + 0]) + pc;
            s[q * 4 + 1] = (av.y + chain_r[q * 4 + 1]) + pc;
            s[q * 4 + 2] = (av.z + chain_r[q * 4 + 2]) + pc;
            s[q * 4 + 3] = (av.w + chain_r[q * 4 + 3]) + pc;
        }
        // tournament 16 -> 1: strict >, left (smaller v) wins ties
        float tv[8]; int ti[8];
#pragma unroll
        for (int i = 0; i < 8; ++i) {
            const bool gt = s[2 * i + 1] > s[2 * i];
            tv[i] = gt ? s[2 * i + 1] : s[2 * i];
            ti[i] = gt ? 2 * i + 1 : 2 * i;
        }
        float uv[4]; int ui[4];
#pragma unroll
        for (int i = 0; i < 4; ++i) {
            const bool gt = tv[2 * i + 1] > tv[2 * i];
            uv[i] = gt ? tv[2 * i + 1] : tv[2 * i];
            ui[i] = gt ? ti[2 * i + 1] : ti[2 * i];
        }
        const bool g0 = uv[1] > uv[0];
        const float w0 = g0 ? uv[1] : uv[0];
        const int   i0 = g0 ? ui[1] : ui[0];
        const bool g1 = uv[3] > uv[2];
        const float w1 = g1 ? uv[3] : uv[2];
        const int   i1 = g1 ? ui[3] : ui[2];
        const bool gf = w1 > w0;
        float bv = gf ? w1 : w0;
        int   gi = vc * 16 + (gf ? i1 : i0);   // global v index

        // quad butterfly via DPP: lex (val, idx) max; equal val -> smaller v
        {
            const float ov = dpp_qp_f<0xB1>(bv);   // xor 1
            const int   oi = dpp_qp_i<0xB1>(gi);
            const bool tk = (ov > bv) || (ov == bv && oi < gi);
            bv = tk ? ov : bv;
            gi = tk ? oi : gi;
        }
        {
            const float ov = dpp_qp_f<0x4E>(bv);   // xor 2
            const int   oi = dpp_qp_i<0x4E>(gi);
            const bool tk = (ov > bv) || (ov == bv && oi < gi);
            bv = tk ? ov : bv;
            gi = tk ? oi : gi;
        }

        if (wr) {
            albuf[t & 1][u] = bv;
            bp[t - 1][u] = (unsigned char)gi;
        }
        __syncthreads();
        pc = pn;
    }

    // ---- backtrace (2-pass segmented, integer-exact, validated) ----
    const int r0c = wv * 128;
    const int r1c = (wv == 3) ? (T_ - 1) : (wv + 1) * 128;

    {   // pass 1: composed map of my segment from every possible start tag
        int tag = lane;
        for (int r = r1c - 1; r >= r0c; --r) tag = bp[r][tag];
        cmap[wv][lane] = (unsigned char)tag;
    }
    __syncthreads();

    if (tid == 0) {
        // final argmax over alpha (first occurrence); last write was buf[1]
        const float* af = albuf[(T_ - 1) & 1];
        float bvv = af[0];
        int bii = 0;
        for (int v = 1; v < 64; ++v) {
            const float a = af[v];
            if (a > bvv) { bvv = a; bii = v; }
        }
        path[(size_t)b * T_ + (T_ - 1)] = bii;
        const int e3 = bii;                 // tag_511
        const int e2 = cmap[3][e3];         // tag_384
        const int e1 = cmap[2][e2];         // tag_256
        const int e0 = cmap[1][e1];         // tag_128
        es[0] = e0; es[1] = e1; es[2] = e2; es[3] = e3;
    }
    __syncthreads();

    // pass 2: 4 parallel chases over disjoint row ranges (exact replica of
    // the sequential loop: tag_r = bp[r][tag_{r+1}], path[r] = tag_r)
    if (lane == 0) {
        int tag = es[wv];                   // tag at row r1c (wv==3: tag_511)
        int* pb = path + (size_t)b * T_;
        for (int r = r1c - 1; r >= r0c; --r) {
            tag = bp[r][tag];
            pb[r] = tag;
        }
    }
}

extern "C" void kernel_launch(void* const* d_in, const int* in_sizes, int n_in,
                              void* d_out, int out_size, void* d_ws, size_t ws_size,
                              hipStream_t stream) {
    const float* x  = (const float*)d_in[0];
    const float* w  = (const float*)d_in[1];
    const float* bs = (const float*)d_in[2];
    const float* ck = (const float*)d_in[3];
    const float* lb = (const float*)d_in[4];
    const float* rb = (const float*)d_in[5];

    float* pot = (float*)d_ws;          // [B*T][U] f32 = 8.39 MB
    int* path  = (int*)d_out;           // [B][T] int32

    crf_gemm_kernel<<<dim3(B_ * T_ / 64), dim3(256), 0, stream>>>(x, w, bs, lb, rb, pot);
    crf_viterbi_kernel<<<dim3(B_), dim3(256), 0, stream>>>(pot, ck, path);
}

// Round 21
// 344.430 us; speedup vs baseline: 1.4597x; 1.1657x over previous
//
#include <hip/hip_runtime.h>

#define B_ 64
#define T_ 512
#define F_ 1024
#define U_ 64
#define FK 128            // k-chunk staged in LDS (GEMM)
#define NCH (F_ / FK)     // 8 chunks

// ---------------------------------------------------------------------------
// Kernel 1: potentials = x @ w + bias (+ boundaries).  32768 x 64.
// VERBATIM round-5 kernel -- best measured GEMM (~110us, validated 6x):
// 64-row block, 4 rows x 4 cols per thread, grid 512 (2 blocks/CU).
// w staged K-chunk-wise into LDS (32 KB), next chunk's loads issued before
// the compute phase. Rolling (non-unrolled) kk loop. Per-output
// accumulation: ascending f, sequential fmaf. DO NOT TOUCH.
// ---------------------------------------------------------------------------
__global__ __launch_bounds__(256, 2) void crf_gemm_kernel(
    const float* __restrict__ x, const float* __restrict__ w,
    const float* __restrict__ bias, const float* __restrict__ lb,
    const float* __restrict__ rb, float* __restrict__ pot)
{
    __shared__ float wlds[FK * U_];     // 32 KB, [k][u] row-major

    const int tid = threadIdx.x;
    const int rt = tid >> 4;            // 16 row-groups x 4 rows
    const int ut = tid & 15;            // 16 col-groups x 4 cols
    const int n0 = blockIdx.x * 64;
    const int r0 = rt * 4;
    const int u0 = ut * 4;

    float acc[4][4];
#pragma unroll
    for (int i = 0; i < 4; ++i)
#pragma unroll
        for (int j = 0; j < 4; ++j) acc[i][j] = 0.f;

    const float* xrow = x + (size_t)(n0 + r0) * F_;

    // ---- stage chunk 0 ----
    float4 wst[8];
#pragma unroll
    for (int l = 0; l < 8; ++l)
        wst[l] = *reinterpret_cast<const float4*>(w + (size_t)(l * 256 + tid) * 4);
#pragma unroll
    for (int l = 0; l < 8; ++l)
        *reinterpret_cast<float4*>(&wlds[(l * 256 + tid) * 4]) = wst[l];
    __syncthreads();

    // ---- x distance-2 register pipeline (global-k indexed) ----
    float4 xp0[4], xp1[4];
#pragma unroll
    for (int i = 0; i < 4; ++i)
        xp0[i] = *reinterpret_cast<const float4*>(xrow + (size_t)i * F_ + 0);
#pragma unroll
    for (int i = 0; i < 4; ++i)
        xp1[i] = *reinterpret_cast<const float4*>(xrow + (size_t)i * F_ + 4);

    for (int c = 0; c < NCH; ++c) {
        // issue next chunk's stage loads early (land during compute)
        if (c + 1 < NCH) {
#pragma unroll
            for (int l = 0; l < 8; ++l)
                wst[l] = *reinterpret_cast<const float4*>(
                    w + (size_t)(c + 1) * (FK * U_) + (size_t)(l * 256 + tid) * 4);
        }

        // w LDS read, prefetched one iter ahead
        float4 wc[4];
#pragma unroll
        for (int j = 0; j < 4; ++j)
            wc[j] = *reinterpret_cast<const float4*>(&wlds[(0 + j) * U_ + u0]);

        for (int kk = 0; kk < FK / 4; ++kk) {
            // prefetch x at global k = c*128 + kk*4 + 8 (wrap: harmless)
            const int kg = (c * FK + kk * 4 + 8) & (F_ - 1);
            float4 xn[4];
#pragma unroll
            for (int i = 0; i < 4; ++i)
                xn[i] = *reinterpret_cast<const float4*>(xrow + (size_t)i * F_ + kg);

            // prefetch next iter's w rows ((kk+1)*4, wraps to 0 at chunk end)
            float4 wn[4];
            const int krn = (kk * 4 + 4) & (FK - 1);
#pragma unroll
            for (int j = 0; j < 4; ++j)
                wn[j] = *reinterpret_cast<const float4*>(&wlds[(krn + j) * U_ + u0]);

            // 64 FMAs, f ascending per output
#pragma unroll
            for (int ff = 0; ff < 4; ++ff) {
                const float4 wf = wc[ff];
#pragma unroll
                for (int i = 0; i < 4; ++i) {
                    const float xs = (ff == 0) ? xp0[i].x : (ff == 1) ? xp0[i].y
                                   : (ff == 2) ? xp0[i].z : xp0[i].w;
                    acc[i][0] = fmaf(xs, wf.x, acc[i][0]);
                    acc[i][1] = fmaf(xs, wf.y, acc[i][1]);
                    acc[i][2] = fmaf(xs, wf.z, acc[i][2]);
                    acc[i][3] = fmaf(xs, wf.w, acc[i][3]);
                }
            }
#pragma unroll
            for (int i = 0; i < 4; ++i) { xp0[i] = xp1[i]; xp1[i] = xn[i]; }
#pragma unroll
            for (int j = 0; j < 4; ++j) wc[j] = wn[j];
        }

        if (c + 1 < NCH) {
            __syncthreads();            // all reads of current chunk done
#pragma unroll
            for (int l = 0; l < 8; ++l)
                *reinterpret_cast<float4*>(&wlds[(l * 256 + tid) * 4]) = wst[l];
            __syncthreads();
        }
    }

    // ---- epilogue ----
    const int t0 = n0 & (T_ - 1);       // 64 | 512: one batch per block
    const float4 bs4 = *reinterpret_cast<const float4*>(bias + u0);
    const float4 lb4 = *reinterpret_cast<const float4*>(lb + u0);
    const float4 rb4 = *reinterpret_cast<const float4*>(rb + u0);

#pragma unroll
    for (int i = 0; i < 4; ++i) {
        const int n = n0 + r0 + i;
        const int t = t0 + r0 + i;
        float4 o;
        o.x = acc[i][0] + bs4.x;
        o.y = acc[i][1] + bs4.y;
        o.z = acc[i][2] + bs4.z;
        o.w = acc[i][3] + bs4.w;
        if (t == 0)      { o.x += lb4.x; o.y += lb4.y; o.z += lb4.z; o.w += lb4.w; }
        if (t == T_ - 1) { o.x += rb4.x; o.y += rb4.y; o.z += rb4.z; o.w += rb4.w; }
        *reinterpret_cast<float4*>(pot + (size_t)n * U_ + u0) = o;
    }
}

// ---------------------------------------------------------------------------
// Kernel 2: Viterbi, one block (4 waves) per batch. VERBATIM R6 kernel --
// best DIRECTLY-MEASURED viterbi (235us, absmax=0): thread (g,u) covers
// v in [g*16, g*16+16); serial 16-candidate compare chain; plain
// __syncthreads x2 per step; distance-1 pot prefetch (drains inside the
// barrier wait -- depth is irrelevant, R10); g0 combines (ascending g,
// strict >) and writes alpha + bp. 11 restructures (DPP, tournament,
// lgkm-barriers, swizzles, co-residency) all measured slower.
// Exact arithmetic: s = (alpha[v] + chain[v][u]) + pot[t][u], strict >,
// ascending v == jnp.argmax first occurrence.
// Segmented 2-pass backtrace (validated, integer-exact).
// ---------------------------------------------------------------------------
__global__ __launch_bounds__(256) void crf_viterbi_kernel(
    const float* __restrict__ pot, const float* __restrict__ chain,
    int* __restrict__ path)
{
    const int b = blockIdx.x;
    const int tid = threadIdx.x;
    const int u = tid & 63;
    const int g = tid >> 6;   // wave 0..3

    __shared__ __align__(16) float alpha_s[64];
    __shared__ float pval[4][64];
    __shared__ int   pidx[4][64];
    __shared__ unsigned char bp[T_ - 1][64];   // 32704 B
    __shared__ unsigned char cmap[4][64];
    __shared__ int es[4];

    float chain_r[16];
#pragma unroll
    for (int k = 0; k < 16; ++k)
        chain_r[k] = chain[(size_t)(g * 16 + k) * U_ + u];

    const float* potb = pot + (size_t)b * T_ * U_;

    if (g == 0) alpha_s[u] = potb[u];          // t = 0 (bias + left included)
    __syncthreads();

    float pc = potb[(size_t)U_ + u];           // pot[1][u]

    for (int t = 1; t < T_; ++t) {
        // prefetch next pot row (hides latency under the inner loop)
        const int tn = (t + 1 < T_) ? (t + 1) : (T_ - 1);
        const float pn = potb[(size_t)tn * U_ + u];

        const float4* a4 = reinterpret_cast<const float4*>(alpha_s);
        float best = -3.402823466e38f;
        int bidx = 0;
#pragma unroll
        for (int q = 0; q < 4; ++q) {
            const float4 av = a4[g * 4 + q];
            const float avv[4] = {av.x, av.y, av.z, av.w};
#pragma unroll
            for (int kk = 0; kk < 4; ++kk) {
                const int k = q * 4 + kk;
                const float s2 = (avv[kk] + chain_r[k]) + pc;
                if (s2 > best) { best = s2; bidx = g * 16 + k; }
            }
        }
        pval[g][u] = best;
        pidx[g][u] = bidx;
        __syncthreads();
        if (g == 0) {
            float bv = pval[0][u];
            int   bi = pidx[0][u];
#pragma unroll
            for (int j = 1; j < 4; ++j) {
                const float v = pval[j][u];
                if (v > bv) { bv = v; bi = pidx[j][u]; }   // strict >: lowest g wins ties
            }
            bp[t - 1][u] = (unsigned char)bi;
            alpha_s[u] = bv;
        }
        __syncthreads();
        pc = pn;
    }

    // ---- backtrace (2-pass segmented, integer-exact, validated) ----
    const int r0c = g * 128;
    const int r1c = (g == 3) ? (T_ - 1) : (g + 1) * 128;

    {   // pass 1: composed map of my segment from every possible start tag
        int tag = u;
        for (int r = r1c - 1; r >= r0c; --r) tag = bp[r][tag];
        cmap[g][u] = (unsigned char)tag;
    }
    __syncthreads();

    if (tid == 0) {
        // final argmax over alpha (first occurrence)
        float bvv = alpha_s[0];
        int bii = 0;
        for (int v = 1; v < 64; ++v) {
            const float a = alpha_s[v];
            if (a > bvv) { bvv = a; bii = v; }
        }
        path[(size_t)b * T_ + (T_ - 1)] = bii;
        const int e3 = bii;                 // tag_511
        const int e2 = cmap[3][e3];         // tag_384
        const int e1 = cmap[2][e2];         // tag_256
        const int e0 = cmap[1][e1];         // tag_128
        es[0] = e0; es[1] = e1; es[2] = e2; es[3] = e3;
    }
    __syncthreads();

    // pass 2: 4 parallel chases over disjoint row ranges (exact replica of
    // the sequential loop: tag_r = bp[r][tag_{r+1}], path[r] = tag_r)
    if (u == 0) {
        int tag = es[g];                    // tag at row r1c (g==3: tag_511)
        int* pb = path + (size_t)b * T_;
        for (int r = r1c - 1; r >= r0c; --r) {
            tag = bp[r][tag];
            pb[r] = tag;
        }
    }
}

extern "C" void kernel_launch(void* const* d_in, const int* in_sizes, int n_in,
                              void* d_out, int out_size, void* d_ws, size_t ws_size,
                              hipStream_t stream) {
    const float* x  = (const float*)d_in[0];
    const float* w  = (const float*)d_in[1];
    const float* bs = (const float*)d_in[2];
    const float* ck = (const float*)d_in[3];
    const float* lb = (const float*)d_in[4];
    const float* rb = (const float*)d_in[5];

    float* pot = (float*)d_ws;          // [B*T][U] f32 = 8.39 MB
    int* path  = (int*)d_out;           // [B][T] int32

    crf_gemm_kernel<<<dim3(B_ * T_ / 64), dim3(256), 0, stream>>>(x, w, bs, lb, rb, pot);
    crf_viterbi_kernel<<<dim3(B_), dim3(256), 0, stream>>>(pot, ck, path);
}